// Round 12
// baseline (575.737 us; speedup 1.0000x reference)
//
#include <hip/hip_runtime.h>

typedef unsigned short u16;
typedef __attribute__((ext_vector_type(4))) float f32x4;
typedef __attribute__((ext_vector_type(8))) short bf16x8;

constexpr int kB  = 4;
constexpr int kT  = 2048;
constexpr int kC  = 1024;
constexpr int kH  = 16;
constexpr int kFF = 4096;
constexpr int kM  = kB * kT;          // 8192 rows
constexpr int k3C = 3 * kC;           // 3072

__device__ __forceinline__ float b2f(u16 u) {
    union { unsigned int i; float f; } v;
    v.i = ((unsigned int)u) << 16;
    return v.f;
}
__device__ __forceinline__ u16 f2b(float f) {
    union { float f; unsigned int i; } v;
    v.f = f;
    unsigned int r = (v.i + 0x7FFFu + ((v.i >> 16) & 1u)) >> 16;
    return (u16)r;
}

// lgkmcnt(0)-only barrier: LDS writes visible at the barrier, but outstanding
// global (vmcnt) prefetch loads stay in flight — enables cross-barrier pipelining.
__device__ __forceinline__ void lds_barrier() {
    __asm__ __volatile__("" ::: "memory");
    __builtin_amdgcn_s_waitcnt(0xC07F);   // vmcnt=63, expcnt=7, lgkmcnt=0
    __builtin_amdgcn_s_barrier();
    __asm__ __volatile__("" ::: "memory");
}

__device__ __forceinline__ void bar_pinned() {
    __builtin_amdgcn_sched_barrier(0);
    __builtin_amdgcn_s_barrier();
    __builtin_amdgcn_sched_barrier(0);
}
__device__ __forceinline__ void lgkm0_pinned() {
    __asm__ __volatile__("s_waitcnt lgkmcnt(0)" ::: "memory");
    __builtin_amdgcn_sched_barrier(0);
}

// ---- f32 -> bf16 convert (x) -------------------------------------------------
__global__ void cvt_f32_bf16(const float* __restrict__ in, u16* __restrict__ out, int n4)
{
    const int i = blockIdx.x * 256 + threadIdx.x;
    if (i >= n4) return;
    float4 v = *(const float4*)(in + (size_t)i * 4);
    ushort4 o;
    o.x = f2b(v.x); o.y = f2b(v.y); o.z = f2b(v.z); o.w = f2b(v.w);
    *(ushort4*)(out + (size_t)i * 4) = o;
}

// ---- generic transpose+convert: in f32 [R][Cc] -> out bf16 [Cc][R] ----------
__global__ void transpose_cvt(const float* __restrict__ in, int R, int Cc,
                              u16* __restrict__ out)
{
    __shared__ float t[32][33];
    const int bx = blockIdx.x * 32;  // col base (Cc)
    const int by = blockIdx.y * 32;  // row base (R)
    const int lx = threadIdx.x, ly = threadIdx.y;  // (32, 8)
    #pragma unroll
    for (int i = 0; i < 32; i += 8)
        t[ly + i][lx] = in[(size_t)(by + ly + i) * Cc + bx + lx];
    __syncthreads();
    #pragma unroll
    for (int i = 0; i < 32; i += 8)
        out[(size_t)(bx + ly + i) * R + by + lx] = f2b(t[lx][ly + i]);
}

// ---- QKV weight repack: Wq/Wk/Wv [H,C,64] f32 -> Wqkv_t [3C][C] bf16 --------
__global__ void repack_qkv_t(const float* __restrict__ Wq, const float* __restrict__ Wk,
                             const float* __restrict__ Wv, u16* __restrict__ out)
{
    __shared__ float t[32][33];
    const int z = blockIdx.z;             // 48 = 3 * 16
    const int s = z >> 4, h = z & 15;
    const float* in = (s == 0 ? Wq : s == 1 ? Wk : Wv) + (size_t)h * (kC * 64);
    const int bx = blockIdx.x * 32;       // d base (0/32)
    const int by = blockIdx.y * 32;       // c base
    const int lx = threadIdx.x, ly = threadIdx.y;  // (32, 8)
    #pragma unroll
    for (int i = 0; i < 32; i += 8)
        t[ly + i][lx] = in[(size_t)(by + ly + i) * 64 + bx + lx];
    __syncthreads();
    const int orow = s * kC + h * 64 + bx;
    #pragma unroll
    for (int i = 0; i < 32; i += 8)
        out[(size_t)(orow + ly + i) * kC + by + lx] = f2b(t[lx][ly + i]);
}

// ---- 256x256 BK=64 8-phase bf16 MFMA GEMM (faithful template port) ----------
// 512 thr / 8 waves (2M x 4N), per-wave out 128x64, LDS 128 KiB:
// As/Bs[2 dbuf][2 half][128x64]. Buffer = tile parity (reuse distance 2).
// Per iteration (tiles t0 even, t0+1): 8 phases, each {ds_read subtile;
// stage ONE half-tile (2 global_load_lds); barrier; lgkmcnt(0); 16 MFMA
// (one 64x32 C-quadrant x K=64) in setprio(1); barrier}. vmcnt(4) only at
// ph4/ph8 — the 2 newest half-tiles stay in flight across barriers (T4).
// Stage ledger (each region staged strictly after the phase whose end-barrier
// retires its last reader): ph1:A0(t0+1) ph2:A1(t0+1) ph3:B0(t0+2)
// ph4:B1(t0+2)+VM4 ph5:A0(t0+2) ph6:A1(t0+2) ph7:B0(t0+3) ph8:B1(t0+3)+VM4.
// A[p] read ph1/ph3 (freed ph3-end); B[p] read ph1-ph2 (freed ph2-end).
// vmcnt(4)@ph4 leaves {B0,B1(t0+2)} => A(t0+1),B(t0+1) landed before ph5.
// vmcnt(4)@ph8 leaves {B0,B1(t0+3)} => A(t0+2),B(t0+2) landed before next ph1.
// Tail (t0+2>=NT): stages skipped, vmcnt degrades to 0. NT must be even.
// LDS swizzle: slot = chunk ^ (row&7)  (== byte ^ ((row&7)<<4), the G4-measured
// fix for 128-B-stride rows); inverse applied on the global source so the
// linear global_load_lds dest stays consistent (both-sides involution).
__global__ __launch_bounds__(512, 2) void gemm_bt_8ph(
    const u16* __restrict__ A, int lda,
    const u16* __restrict__ Bt, int ldb,
    int K,
    const float* __restrict__ bias,
    const u16* __restrict__ resid,
    float* __restrict__ CoF,
    u16* __restrict__ CoB,
    int ldc, int do_relu, int nbx)
{
    __shared__ __align__(16) u16 As[2][2][128 * 64];   // 64 KiB
    __shared__ __align__(16) u16 Bs[2][2][128 * 64];   // 64 KiB

    const int tid  = threadIdx.x;
    const int wave = tid >> 6, lane = tid & 63;
    const int wm = wave >> 2, wn = wave & 3;           // 2M x 4N

    const int cpx = gridDim.x >> 3;
    const int swz = (blockIdx.x & 7) * cpx + (blockIdx.x >> 3);
    const int bx = swz % nbx, by = swz / nbx;
    const int m0 = by * 256, n0 = bx * 256;

    const int srow = tid >> 3, sc = tid & 7;           // staging geometry
    const int fm = lane & 15, fkq = lane >> 4;

    f32x4 acc[8][4];
    #pragma unroll
    for (int i = 0; i < 8; ++i)
        #pragma unroll
        for (int j = 0; j < 4; ++j)
            acc[i][j] = (f32x4){0.f, 0.f, 0.f, 0.f};

    const int NT = K >> 6;                // BK = 64 (NT even required)
    const int NI = NT >> 1;

    auto stageHalf = [&](const u16* g, int ld, u16* lh) {
        {
            const int row = srow;                       // rows 0..63
            const int cg  = (sc ^ (row & 7)) * 8;
            __builtin_amdgcn_global_load_lds(
                (const __attribute__((address_space(1))) void*)(g + (size_t)row * ld + cg),
                (__attribute__((address_space(3))) void*)(lh + tid * 8), 16, 0, 0);
        }
        {
            const int row = 64 + srow;                  // rows 64..127
            const int cg  = (sc ^ (row & 7)) * 8;
            __builtin_amdgcn_global_load_lds(
                (const __attribute__((address_space(1))) void*)(g + (size_t)row * ld + cg),
                (__attribute__((address_space(3))) void*)(lh + 4096 + tid * 8), 16, 0, 0);
        }
    };
    auto stA = [&](int kt, int ha) {
        stageHalf(A + (size_t)(m0 + ha * 128) * lda + kt * 64, lda, As[kt & 1][ha]);
    };
    auto stB = [&](int kt, int hb) {
        stageHalf(Bt + (size_t)(n0 + hb * 128) * ldb + kt * 64, ldb, Bs[kt & 1][hb]);
    };

    auto rdA = [&](bf16x8 (&a)[4][2], int db, int qm) {
        #pragma unroll
        for (int i = 0; i < 4; ++i) {
            const int ra = qm * 64 + i * 16 + fm;
            #pragma unroll
            for (int ks = 0; ks < 2; ++ks) {
                const int slot = (ks * 4 + fkq) ^ (ra & 7);
                a[i][ks] = *(const bf16x8*)&As[db][wm][ra * 64 + slot * 8];
            }
        }
    };
    auto rdB = [&](bf16x8 (&b)[2][2], int db, int qn) {
        #pragma unroll
        for (int j = 0; j < 2; ++j) {
            const int rb = (wn & 1) * 64 + qn * 32 + j * 16 + fm;
            #pragma unroll
            for (int ks = 0; ks < 2; ++ks) {
                const int slot = (ks * 4 + fkq) ^ (rb & 7);
                b[j][ks] = *(const bf16x8*)&Bs[db][wn >> 1][rb * 64 + slot * 8];
            }
        }
    };
    auto mm = [&](bf16x8 (&a)[4][2], bf16x8 (&b)[2][2], int qm, int qn) {
        __builtin_amdgcn_s_setprio(1);
        #pragma unroll
        for (int ks = 0; ks < 2; ++ks)
            #pragma unroll
            for (int i = 0; i < 4; ++i)
                #pragma unroll
                for (int j = 0; j < 2; ++j)
                    acc[qm * 4 + i][qn * 2 + j] = __builtin_amdgcn_mfma_f32_16x16x32_bf16(
                        a[i][ks], b[j][ks], acc[qm * 4 + i][qn * 2 + j], 0, 0, 0);
        __builtin_amdgcn_s_setprio(0);
    };

    // prologue: A(0), B(0), B(1); drain to leave B(1)'s 4 loads in flight
    stA(0, 0); stA(0, 1); stB(0, 0); stB(0, 1);
    if (NT > 1) {
        stB(1, 0); stB(1, 1);
        __builtin_amdgcn_sched_barrier(0);
        __asm__ __volatile__("s_waitcnt vmcnt(4)" ::: "memory");
    } else {
        __builtin_amdgcn_sched_barrier(0);
        __asm__ __volatile__("s_waitcnt vmcnt(0)" ::: "memory");
    }
    bar_pinned();

    bf16x8 aL[4][2], aH[4][2], bL[2][2], bH[2][2];
    for (int it = 0; it < NI; ++it) {
        const int t0 = 2 * it;
        // ---- tile t0 (buffers [0]) ----
        // ph1
        rdA(aL, 0, 0); rdB(bL, 0, 0);
        stA(t0 + 1, 0);
        bar_pinned(); lgkm0_pinned();
        mm(aL, bL, 0, 0);
        bar_pinned();
        // ph2
        rdB(bH, 0, 1);
        stA(t0 + 1, 1);
        bar_pinned(); lgkm0_pinned();
        mm(aL, bH, 0, 1);
        bar_pinned();
        // ph3
        rdA(aH, 0, 1);
        if (t0 + 2 < NT) stB(t0 + 2, 0);
        bar_pinned(); lgkm0_pinned();
        mm(aH, bH, 1, 1);
        bar_pinned();
        // ph4
        if (t0 + 2 < NT) {
            stB(t0 + 2, 1);
            __builtin_amdgcn_sched_barrier(0);
            __asm__ __volatile__("s_waitcnt vmcnt(4)" ::: "memory");
        } else {
            __builtin_amdgcn_sched_barrier(0);
            __asm__ __volatile__("s_waitcnt vmcnt(0)" ::: "memory");
        }
        bar_pinned();
        mm(aH, bL, 1, 0);
        bar_pinned();
        // ---- tile t0+1 (buffers [1]) ----
        // ph5
        rdA(aL, 1, 0); rdB(bL, 1, 0);
        if (t0 + 2 < NT) stA(t0 + 2, 0);
        bar_pinned(); lgkm0_pinned();
        mm(aL, bL, 0, 0);
        bar_pinned();
        // ph6
        rdB(bH, 1, 1);
        if (t0 + 2 < NT) stA(t0 + 2, 1);
        bar_pinned(); lgkm0_pinned();
        mm(aL, bH, 0, 1);
        bar_pinned();
        // ph7
        rdA(aH, 1, 1);
        if (t0 + 3 < NT) stB(t0 + 3, 0);
        bar_pinned(); lgkm0_pinned();
        mm(aH, bH, 1, 1);
        bar_pinned();
        // ph8
        if (t0 + 3 < NT) stB(t0 + 3, 1);
        if (it + 1 < NI) {
            __builtin_amdgcn_sched_barrier(0);
            __asm__ __volatile__("s_waitcnt vmcnt(4)" ::: "memory");
        }
        bar_pinned();
        mm(aH, bL, 1, 0);
        bar_pinned();
    }

    // epilogue: m = m0 + wm*128 + qm*64 + ii*16 + (lane>>4)*4 + r; n = n0 + wn*64 + qn*32 + jj*16 + col
    const int col = lane & 15;
    const int rb4 = (lane >> 4) * 4;
    #pragma unroll
    for (int i8 = 0; i8 < 8; ++i8) {
        const int mb = m0 + wm * 128 + (i8 >> 2) * 64 + (i8 & 3) * 16 + rb4;
        #pragma unroll
        for (int j4 = 0; j4 < 4; ++j4) {
            const int n = n0 + wn * 64 + (j4 >> 1) * 32 + (j4 & 1) * 16 + col;
            #pragma unroll
            for (int r = 0; r < 4; ++r) {
                const int m = mb + r;
                float v = acc[i8][j4][r];
                if (bias)    v += bias[n];
                if (do_relu) v = fmaxf(v, 0.f);
                if (resid)   v += b2f(resid[(size_t)m * ldc + n]);
                if (CoF) CoF[(size_t)m * ldc + n] = v;
                else     CoB[(size_t)m * ldc + n] = f2b(v);
            }
        }
    }
}

// ---- 256x128 BK=32 ring-3 bf16 MFMA GEMM (round-4 verified, session best) ---
__global__ __launch_bounds__(512, 4) void gemm_bt_k32r(
    const u16* __restrict__ A, int lda,
    const u16* __restrict__ Bt, int ldb,
    int K,
    const float* __restrict__ bias,
    const u16* __restrict__ resid,
    float* __restrict__ CoF,
    u16* __restrict__ CoB,
    int ldc, int do_relu, int nbx)
{
    __shared__ __align__(16) u16 As[3][256 * 32];   // 3 x 16 KiB
    __shared__ __align__(16) u16 Bs[3][128 * 32];   // 3 x  8 KiB

    const int tid  = threadIdx.x;
    const int wave = tid >> 6, lane = tid & 63;
    const int wm = (wave >> 1) * 64, wn = (wave & 1) * 64;

    const int cpx = gridDim.x >> 3;
    const int swz = (blockIdx.x & 7) * cpx + (blockIdx.x >> 3);
    const int bx = swz % nbx, by = swz / nbx;
    const int m0 = by * 256, n0 = bx * 128;

    const int rl = tid >> 2;
    const int cg = ((tid & 3) ^ ((tid >> 3) & 3)) * 8;

    const int fm = lane & 15, fkq = lane >> 4;
    const int fchunk = (fkq ^ ((fm >> 1) & 3)) * 8;

    f32x4 acc[4][4];
    #pragma unroll
    for (int i = 0; i < 4; ++i)
        #pragma unroll
        for (int j = 0; j < 4; ++j)
            acc[i][j] = (f32x4){0.f, 0.f, 0.f, 0.f};

    const int NT = K >> 5;                // BK = 32

    auto stg = [&](const u16* g, int ld, int r0, u16* l) {
        __builtin_amdgcn_global_load_lds(
            (const __attribute__((address_space(1))) void*)(g + (size_t)(r0 + rl) * ld + cg),
            (__attribute__((address_space(3))) void*)(l + r0 * 32 + tid * 8), 16, 0, 0);
    };
    auto stageAB = [&](int kt, int slot) {   // exactly 3 loads/thread = 24 KB
        const u16* ga = A  + (size_t)m0 * lda + kt * 32;
        const u16* gb = Bt + (size_t)n0 * ldb + kt * 32;
        stg(ga, lda, 0,   As[slot]);
        stg(ga, lda, 128, As[slot]);
        stg(gb, ldb, 0,   Bs[slot]);
    };

    stageAB(0, 0);
    if (NT > 1) {
        stageAB(1, 1);
        __builtin_amdgcn_sched_barrier(0);
        __asm__ __volatile__("s_waitcnt vmcnt(3)" ::: "memory");
    } else {
        __builtin_amdgcn_sched_barrier(0);
        __asm__ __volatile__("s_waitcnt vmcnt(0)" ::: "memory");
    }
    __builtin_amdgcn_s_barrier();
    __builtin_amdgcn_sched_barrier(0);

    int cur = 0;
    for (int t = 0; t < NT; ++t) {
        const int sst = (cur == 0) ? 2 : cur - 1;   // (t+2) % 3
        if (t + 2 < NT) stageAB(t + 2, sst);
        const u16* Sa = As[cur];
        const u16* Sb = Bs[cur];
        bf16x8 a[4], b[4];
        #pragma unroll
        for (int i = 0; i < 4; ++i) {
            const int m = wm + i * 16 + fm;
            a[i] = *(const bf16x8*)&Sa[m * 32 + fchunk];
        }
        #pragma unroll
        for (int j = 0; j < 4; ++j) {
            const int n = wn + j * 16 + fm;
            b[j] = *(const bf16x8*)&Sb[n * 32 + fchunk];
        }
        __builtin_amdgcn_s_setprio(1);
        #pragma unroll
        for (int i = 0; i < 4; ++i)
            #pragma unroll
            for (int j = 0; j < 4; ++j)
                acc[i][j] = __builtin_amdgcn_mfma_f32_16x16x32_bf16(
                    a[i], b[j], acc[i][j], 0, 0, 0);
        __builtin_amdgcn_s_setprio(0);
        if (t + 1 < NT) {
            __builtin_amdgcn_sched_barrier(0);
            if (t + 2 < NT) { __asm__ __volatile__("s_waitcnt vmcnt(3)" ::: "memory"); }
            else            { __asm__ __volatile__("s_waitcnt vmcnt(0)" ::: "memory"); }
            __builtin_amdgcn_s_barrier();
            __builtin_amdgcn_sched_barrier(0);
        }
        cur = (cur == 2) ? 0 : cur + 1;
    }

    const int col = lane & 15;
    const int rb  = (lane >> 4) * 4;
    #pragma unroll
    for (int i = 0; i < 4; ++i) {
        #pragma unroll
        for (int j = 0; j < 4; ++j) {
            const int n = n0 + wn + j * 16 + col;
            #pragma unroll
            for (int r = 0; r < 4; ++r) {
                const int m = m0 + wm + i * 16 + rb + r;
                float v = acc[i][j][r];
                if (bias)    v += bias[n];
                if (do_relu) v = fmaxf(v, 0.f);
                if (resid)   v += b2f(resid[(size_t)m * ldc + n]);
                if (CoF) CoF[(size_t)m * ldc + n] = v;
                else     CoB[(size_t)m * ldc + n] = f2b(v);
            }
        }
    }
}

// ---- MFMA flash attention v3 + T5 setprio + T13 defer-max (round-9 best) ----
// NOTE (r10): no branches inside the unrolled QK/exp loops — breaks the
// static schedule (+4.3M bank conflicts, VGPR 132, attn 125->172 us).
__global__ __launch_bounds__(256) void attn_mfma3(
    const u16* __restrict__ QKV, u16* __restrict__ Y)
{
    __shared__ __align__(16) u16 Kl[2][64 * 64];     // 16 KB
    __shared__ __align__(16) u16 Vt[2][64 * 64];     // 16 KB (transposed [d][s])
    __shared__ __align__(16) u16 Pl[4][16 * 64];     // 8 KB per-wave P^T [q][s]

    const int tid  = threadIdx.x;
    const int wave = tid >> 6, lane = tid & 63;
    const int ln = lane & 15, quad = lane >> 4;
    const int idx = blockIdx.x;
    const int bh = idx & 63;                         // same bh -> same idx%8 (XCD)
    const int qt = 15 - (idx >> 6);                  // heavy q-tiles dispatch first
    const int b = bh >> 4, h = bh & 15;
    const int q0 = qt << 7;
    const int bT = b * kT;
    const int qgw = q0 + wave * 32;
    const float scale = 0.03125f;                    // 1024^-0.5 (full embed dim)

    const u16* kvbase = QKV + (size_t)bT * k3C + kC + h * 64;  // K base (V = +kC)

    const int sK = tid >> 3, cK = tid & 7;
    const int sV = (tid >> 3) * 2, cV = tid & 7;
    const int kwa0 = (sK << 6) + ((cK ^ (sK & 7)) << 3);
    const int kwa1 = kwa0 + (32 << 6);

    bf16x8 qa[2][2];
    #pragma unroll
    for (int qsub = 0; qsub < 2; ++qsub) {
        const size_t qb = ((size_t)bT + qgw + 16 * qsub + ln) * k3C + h * 64;
        qa[qsub][0] = *(const bf16x8*)(QKV + qb + quad * 8);
        qa[qsub][1] = *(const bf16x8*)(QKV + qb + 32 + quad * 8);
    }

    f32x4 acco[2][4];
    #pragma unroll
    for (int qsub = 0; qsub < 2; ++qsub)
        #pragma unroll
        for (int jd = 0; jd < 4; ++jd) acco[qsub][jd] = (f32x4){0.f, 0.f, 0.f, 0.f};
    float mrun[2] = {-1e30f, -1e30f}, lrun[2] = {0.f, 0.f};
    u16* Pw = Pl[wave];

    const int ntiles = 2 * qt + 2;                   // always even

    auto loadkv = [&](int s0p, uint4& k0, uint4& k1, uint4& v0, uint4& v1) {
        const u16* kg = kvbase + (size_t)(s0p + sK) * k3C + cK * 8;
        k0 = *(const uint4*)kg;
        k1 = *(const uint4*)(kg + (size_t)32 * k3C);
        const u16* vg = kvbase + kC + (size_t)(s0p + sV) * k3C + cV * 8;
        v0 = *(const uint4*)vg;
        v1 = *(const uint4*)(vg + k3C);
    };
    auto stage = [&](u16* Kb, u16* Vb, const uint4& k0, const uint4& k1,
                     const uint4& v0, const uint4& v1) {
        *(uint4*)&Kb[kwa0] = k0;
        *(uint4*)&Kb[kwa1] = k1;
        const u16* t0 = (const u16*)&v0;
        const u16* t1 = (const u16*)&v1;
        #pragma unroll
        for (int i = 0; i < 8; ++i) {
            const int d = cV * 8 + i;
            const int chunk = ((sV >> 3) ^ (d & 7) ^ ((d >> 3) & 7)) & 7;
            ushort2 pr; pr.x = t0[i]; pr.y = t1[i];
            *(ushort2*)&Vb[(d << 6) + (chunk << 3) + (sV & 7)] = pr;
        }
    };
    auto compute = [&](int t, const u16* Kb, const u16* Vb) {
        const int s0 = t << 6;
        if (s0 > qgw + 31) return;                   // wave fully masked this tile
        f32x4 accs[2][4];
        #pragma unroll
        for (int qsub = 0; qsub < 2; ++qsub)
            #pragma unroll
            for (int j = 0; j < 4; ++j) accs[qsub][j] = (f32x4){0.f, 0.f, 0.f, 0.f};
        __builtin_amdgcn_s_setprio(1);               // T5: QK cluster
        #pragma unroll
        for (int ks = 0; ks < 2; ++ks) {
            #pragma unroll
            for (int j = 0; j < 4; ++j) {
                const int s = j * 16 + ln;
                bf16x8 kb = *(const bf16x8*)&Kb[(s << 6) + ((((quad + 4 * ks) ^ (s & 7)) & 7) << 3)];
                accs[0][j] = __builtin_amdgcn_mfma_f32_16x16x32_bf16(kb, qa[0][ks], accs[0][j], 0, 0, 0);
                accs[1][j] = __builtin_amdgcn_mfma_f32_16x16x32_bf16(kb, qa[1][ks], accs[1][j], 0, 0, 0);
            }
        }
        __builtin_amdgcn_s_setprio(0);
        bf16x8 vfr[4][2];
        #pragma unroll
        for (int jd = 0; jd < 4; ++jd) {
            const int d = jd * 16 + ln;
            #pragma unroll
            for (int ks = 0; ks < 2; ++ks)
                vfr[jd][ks] = *(const bf16x8*)&Vb[(d << 6) + ((((quad + 4 * ks) ^ (d & 7) ^ ((d >> 3) & 7)) & 7) << 3)];
        }
        #pragma unroll
        for (int qsub = 0; qsub < 2; ++qsub) {
            const int qg = qgw + 16 * qsub + ln;
            float part = -1e30f;
            #pragma unroll
            for (int j = 0; j < 4; ++j) {
                #pragma unroll
                for (int r = 0; r < 4; ++r) {
                    const int sg = s0 + j * 16 + quad * 4 + r;
                    float v = accs[qsub][j][r] * scale;
                    v = (sg <= qg) ? v : -1e30f;
                    accs[qsub][j][r] = v;
                    part = fmaxf(part, v);
                }
            }
            float mx = fmaxf(part, __shfl_xor(part, 16));
            mx = fmaxf(mx, __shfl_xor(mx, 32));
            const bool skip = __all(mx - mrun[qsub] <= 8.0f);
            const float mn = skip ? mrun[qsub] : fmaxf(mrun[qsub], mx);
            float ls = 0.f;
            #pragma unroll
            for (int j = 0; j < 4; ++j)
                #pragma unroll
                for (int r = 0; r < 4; ++r) {
                    const float p = __expf(accs[qsub][j][r] - mn);
                    accs[qsub][j][r] = p;
                    ls += p;
                }
            ls += __shfl_xor(ls, 16);
            ls += __shfl_xor(ls, 32);
            if (skip) {
                lrun[qsub] += ls;
            } else {
                const float al = __expf(mrun[qsub] - mn);
                mrun[qsub] = mn;
                lrun[qsub] = lrun[qsub] * al + ls;
                #pragma unroll
                for (int jd = 0; jd < 4; ++jd)
                    #pragma unroll
                    for (int r = 0; r < 4; ++r)
                        acco[qsub][jd][r] *= al;
            }
            #pragma unroll
            for (int j = 0; j < 4; ++j) {
                ushort4 pk;
                pk.x = f2b(accs[qsub][j][0]); pk.y = f2b(accs[qsub][j][1]);
                pk.z = f2b(accs[qsub][j][2]); pk.w = f2b(accs[qsub][j][3]);
                const int chunk = ((2 * j + (quad >> 1)) ^ (ln & 7)) & 7;
                *(ushort4*)&Pw[(ln << 6) + (chunk << 3) + ((quad & 1) << 2)] = pk;
            }
            __builtin_amdgcn_s_setprio(1);           // T5: PV cluster
            #pragma unroll
            for (int ks = 0; ks < 2; ++ks) {
                bf16x8 pb = *(const bf16x8*)&Pw[(ln << 6) + ((((4 * ks + quad) ^ (ln & 7)) & 7) << 3)];
                #pragma unroll
                for (int jd = 0; jd < 4; ++jd)
                    acco[qsub][jd] = __builtin_amdgcn_mfma_f32_16x16x32_bf16(
                        vfr[jd][ks], pb, acco[qsub][jd], 0, 0, 0);
            }
            __builtin_amdgcn_s_setprio(0);
        }
    };

    uint4 ka0, ka1, va0, va1, kb0, kb1, vb0, vb1;
    loadkv(0, ka0, ka1, va0, va1);
    for (int t = 0; t < ntiles; t += 2) {
        stage(Kl[0], Vt[0], ka0, ka1, va0, va1);
        loadkv((t + 1) << 6, kb0, kb1, vb0, vb1);    // t+1 < ntiles (ntiles even)
        lds_barrier();
        compute(t, Kl[0], Vt[0]);
        stage(Kl[1], Vt[1], kb0, kb1, vb0, vb1);
        loadkv(((t + 2) < ntiles ? (t + 2) : 0) << 6, ka0, ka1, va0, va1);
        lds_barrier();
        compute(t + 1, Kl[1], Vt[1]);
    }

    #pragma unroll
    for (int qsub = 0; qsub < 2; ++qsub) {
        const float inv = 1.f / lrun[qsub];
        const size_t yrow = ((size_t)bT + qgw + 16 * qsub + ln) * kC + h * 64;
        #pragma unroll
        for (int jd = 0; jd < 4; ++jd) {
            ushort4 ov;
            ov.x = f2b(acco[qsub][jd][0] * inv);
            ov.y = f2b(acco[qsub][jd][1] * inv);
            ov.z = f2b(acco[qsub][jd][2] * inv);
            ov.w = f2b(acco[qsub][jd][3] * inv);
            *(ushort4*)(Y + yrow + jd * 16 + quad * 4) = ov;
        }
    }
}

extern "C" void kernel_launch(void* const* d_in, const int* in_sizes, int n_in,
                              void* d_out, int out_size, void* d_ws, size_t ws_size,
                              hipStream_t stream) {
    const float* x     = (const float*)d_in[0];
    const float* Wq    = (const float*)d_in[1];
    const float* Wk    = (const float*)d_in[2];
    const float* Wv    = (const float*)d_in[3];
    const float* Wproj = (const float*)d_in[4];
    const float* bproj = (const float*)d_in[5];
    const float* W1    = (const float*)d_in[6];
    const float* b1    = (const float*)d_in[7];
    const float* W2    = (const float*)d_in[8];
    const float* b2    = (const float*)d_in[9];

    // Workspace (bf16 elements). QKV (live 2-3) aliases ffh (live 5-6).
    u16* ws      = (u16*)d_ws;
    u16* QKV     = ws;                                  // [8192,3072]
    u16* ffh     = ws;                                  // [8192,4096]
    u16* attn_y  = ws + (size_t)kM * kFF;               // [8192,1024]
    u16* xb      = attn_y  + (size_t)kM * kC;           // [8192,1024]
    u16* res1    = xb      + (size_t)kM * kC;           // [8192,1024]
    u16* Wqkv_t  = res1    + (size_t)kM * kC;           // [3072,1024]
    u16* Wproj_t = Wqkv_t  + (size_t)k3C * kC;          // [1024,1024]
    u16* W1t     = Wproj_t + (size_t)kC * kC;           // [4096,1024]
    u16* W2t     = W1t     + (size_t)kFF * kC;          // [1024,4096]
    float* out   = (float*)d_out;

    // 0. converts / repacks
    cvt_f32_bf16<<<(kM * kC / 4 + 255) / 256, 256, 0, stream>>>(x, xb, kM * kC / 4);
    repack_qkv_t<<<dim3(2, kC / 32, 48), dim3(32, 8), 0, stream>>>(Wq, Wk, Wv, Wqkv_t);
    transpose_cvt<<<dim3(kC / 32, kC / 32),  dim3(32, 8), 0, stream>>>(Wproj, kC, kC, Wproj_t);
    transpose_cvt<<<dim3(kFF / 32, kC / 32), dim3(32, 8), 0, stream>>>(W1, kC, kFF, W1t);
    transpose_cvt<<<dim3(kC / 32, kFF / 32), dim3(32, 8), 0, stream>>>(W2, kFF, kC, W2t);

    // 1. QKV = xb @ Wqkv_t^T        (32*24 = 768 blocks)
    gemm_bt_k32r<<<dim3((kM / 256) * (k3C / 128)), 512, 0, stream>>>(
        xb, kC, Wqkv_t, kC, kC, nullptr, nullptr, nullptr, QKV, k3C, 0, k3C / 128);
    // 2. attention -> attn_y bf16
    attn_mfma3<<<dim3(1024), 256, 0, stream>>>(QKV, attn_y);
    // 3. res1 = attn_y @ Wproj + bproj + xb   (32*8 = 256 blocks)
    gemm_bt_k32r<<<dim3((kM / 256) * (kC / 128)), 512, 0, stream>>>(
        attn_y, kC, Wproj_t, kC, kC, bproj, xb, nullptr, res1, kC, 0, kC / 128);
    // 4. ffh = relu(res1 @ W1 + b1)   (32*16 = 512 blocks, 256x256 8-PHASE)
    gemm_bt_8ph<<<dim3((kM / 256) * (kFF / 256)), 512, 0, stream>>>(
        res1, kC, W1t, kC, kC, b1, nullptr, nullptr, ffh, kFF, 1, kFF / 256);
    // 5. out = ffh @ W2 + b2 + res1 -> f32    (32*8 = 256 blocks)
    gemm_bt_k32r<<<dim3((kM / 256) * (kC / 128)), 512, 0, stream>>>(
        ffh, kFF, W2t, kFF, kFF, b2, res1, out, nullptr, kC, 0, kC / 128);
}

// Round 13
// 557.522 us; speedup vs baseline: 1.0327x; 1.0327x over previous
//
#include <hip/hip_runtime.h>

typedef unsigned short u16;
typedef __attribute__((ext_vector_type(4))) float f32x4;
typedef __attribute__((ext_vector_type(8))) short bf16x8;

constexpr int kB  = 4;
constexpr int kT  = 2048;
constexpr int kC  = 1024;
constexpr int kH  = 16;
constexpr int kFF = 4096;
constexpr int kM  = kB * kT;          // 8192 rows
constexpr int k3C = 3 * kC;           // 3072

__device__ __forceinline__ float b2f(u16 u) {
    union { unsigned int i; float f; } v;
    v.i = ((unsigned int)u) << 16;
    return v.f;
}
__device__ __forceinline__ u16 f2b(float f) {
    union { float f; unsigned int i; } v;
    v.f = f;
    unsigned int r = (v.i + 0x7FFFu + ((v.i >> 16) & 1u)) >> 16;
    return (u16)r;
}

// lgkmcnt(0)-only barrier: LDS writes visible at the barrier, but outstanding
// global (vmcnt) prefetch loads stay in flight — enables cross-barrier pipelining.
__device__ __forceinline__ void lds_barrier() {
    __asm__ __volatile__("" ::: "memory");
    __builtin_amdgcn_s_waitcnt(0xC07F);   // vmcnt=63, expcnt=7, lgkmcnt=0
    __builtin_amdgcn_s_barrier();
    __asm__ __volatile__("" ::: "memory");
}

// ---- f32 -> bf16 convert (x) -------------------------------------------------
__global__ void cvt_f32_bf16(const float* __restrict__ in, u16* __restrict__ out, int n4)
{
    const int i = blockIdx.x * 256 + threadIdx.x;
    if (i >= n4) return;
    float4 v = *(const float4*)(in + (size_t)i * 4);
    ushort4 o;
    o.x = f2b(v.x); o.y = f2b(v.y); o.z = f2b(v.z); o.w = f2b(v.w);
    *(ushort4*)(out + (size_t)i * 4) = o;
}

// ---- generic transpose+convert: in f32 [R][Cc] -> out bf16 [Cc][R] ----------
__global__ void transpose_cvt(const float* __restrict__ in, int R, int Cc,
                              u16* __restrict__ out)
{
    __shared__ float t[32][33];
    const int bx = blockIdx.x * 32;  // col base (Cc)
    const int by = blockIdx.y * 32;  // row base (R)
    const int lx = threadIdx.x, ly = threadIdx.y;  // (32, 8)
    #pragma unroll
    for (int i = 0; i < 32; i += 8)
        t[ly + i][lx] = in[(size_t)(by + ly + i) * Cc + bx + lx];
    __syncthreads();
    #pragma unroll
    for (int i = 0; i < 32; i += 8)
        out[(size_t)(bx + ly + i) * R + by + lx] = f2b(t[lx][ly + i]);
}

// ---- QKV weight repack: Wq/Wk/Wv [H,C,64] f32 -> Wqkv_t [3C][C] bf16 --------
__global__ void repack_qkv_t(const float* __restrict__ Wq, const float* __restrict__ Wk,
                             const float* __restrict__ Wv, u16* __restrict__ out)
{
    __shared__ float t[32][33];
    const int z = blockIdx.z;             // 48 = 3 * 16
    const int s = z >> 4, h = z & 15;
    const float* in = (s == 0 ? Wq : s == 1 ? Wk : Wv) + (size_t)h * (kC * 64);
    const int bx = blockIdx.x * 32;       // d base (0/32)
    const int by = blockIdx.y * 32;       // c base
    const int lx = threadIdx.x, ly = threadIdx.y;  // (32, 8)
    #pragma unroll
    for (int i = 0; i < 32; i += 8)
        t[ly + i][lx] = in[(size_t)(by + ly + i) * 64 + bx + lx];
    __syncthreads();
    const int orow = s * kC + h * 64 + bx;
    #pragma unroll
    for (int i = 0; i < 32; i += 8)
        out[(size_t)(orow + ly + i) * kC + by + lx] = f2b(t[lx][ly + i]);
}

// ---- 256x128 BK=32 ring-3 bf16 MFMA GEMM (round-4 verified, session best) ---
// 512 thr / 8 waves (4M x 2N), per-wave 64x64 out, 72 KiB 3-deep ring LDS.
// Counted-vmcnt ring: stage(t+2) -> compute(t) -> vmcnt(3) -> barrier.
// Session note: thirteen structural variants (tile/BK/occupancy/phases/
// split-K/MFMA-shape) all land at the same ~500 TF invariant or below;
// this is the reproducible optimum of the family under hipcc.
__global__ __launch_bounds__(512, 4) void gemm_bt_k32r(
    const u16* __restrict__ A, int lda,
    const u16* __restrict__ Bt, int ldb,
    int K,
    const float* __restrict__ bias,
    const u16* __restrict__ resid,
    float* __restrict__ CoF,
    u16* __restrict__ CoB,
    int ldc, int do_relu, int nbx)
{
    __shared__ __align__(16) u16 As[3][256 * 32];   // 3 x 16 KiB
    __shared__ __align__(16) u16 Bs[3][128 * 32];   // 3 x  8 KiB

    const int tid  = threadIdx.x;
    const int wave = tid >> 6, lane = tid & 63;
    const int wm = (wave >> 1) * 64, wn = (wave & 1) * 64;

    const int cpx = gridDim.x >> 3;
    const int swz = (blockIdx.x & 7) * cpx + (blockIdx.x >> 3);
    const int bx = swz % nbx, by = swz / nbx;
    const int m0 = by * 256, n0 = bx * 128;

    const int rl = tid >> 2;
    const int cg = ((tid & 3) ^ ((tid >> 3) & 3)) * 8;

    const int fm = lane & 15, fkq = lane >> 4;
    const int fchunk = (fkq ^ ((fm >> 1) & 3)) * 8;

    f32x4 acc[4][4];
    #pragma unroll
    for (int i = 0; i < 4; ++i)
        #pragma unroll
        for (int j = 0; j < 4; ++j)
            acc[i][j] = (f32x4){0.f, 0.f, 0.f, 0.f};

    const int NT = K >> 5;                // BK = 32

    auto stg = [&](const u16* g, int ld, int r0, u16* l) {
        __builtin_amdgcn_global_load_lds(
            (const __attribute__((address_space(1))) void*)(g + (size_t)(r0 + rl) * ld + cg),
            (__attribute__((address_space(3))) void*)(l + r0 * 32 + tid * 8), 16, 0, 0);
    };
    auto stageAB = [&](int kt, int slot) {   // exactly 3 loads/thread = 24 KB
        const u16* ga = A  + (size_t)m0 * lda + kt * 32;
        const u16* gb = Bt + (size_t)n0 * ldb + kt * 32;
        stg(ga, lda, 0,   As[slot]);
        stg(ga, lda, 128, As[slot]);
        stg(gb, ldb, 0,   Bs[slot]);
    };

    stageAB(0, 0);
    if (NT > 1) {
        stageAB(1, 1);
        __builtin_amdgcn_sched_barrier(0);
        __asm__ __volatile__("s_waitcnt vmcnt(3)" ::: "memory");
    } else {
        __builtin_amdgcn_sched_barrier(0);
        __asm__ __volatile__("s_waitcnt vmcnt(0)" ::: "memory");
    }
    __builtin_amdgcn_s_barrier();
    __builtin_amdgcn_sched_barrier(0);

    int cur = 0;
    for (int t = 0; t < NT; ++t) {
        const int sst = (cur == 0) ? 2 : cur - 1;   // (t+2) % 3
        if (t + 2 < NT) stageAB(t + 2, sst);
        const u16* Sa = As[cur];
        const u16* Sb = Bs[cur];
        bf16x8 a[4], b[4];
        #pragma unroll
        for (int i = 0; i < 4; ++i) {
            const int m = wm + i * 16 + fm;
            a[i] = *(const bf16x8*)&Sa[m * 32 + fchunk];
        }
        #pragma unroll
        for (int j = 0; j < 4; ++j) {
            const int n = wn + j * 16 + fm;
            b[j] = *(const bf16x8*)&Sb[n * 32 + fchunk];
        }
        __builtin_amdgcn_s_setprio(1);
        #pragma unroll
        for (int i = 0; i < 4; ++i)
            #pragma unroll
            for (int j = 0; j < 4; ++j)
                acc[i][j] = __builtin_amdgcn_mfma_f32_16x16x32_bf16(
                    a[i], b[j], acc[i][j], 0, 0, 0);
        __builtin_amdgcn_s_setprio(0);
        if (t + 1 < NT) {
            __builtin_amdgcn_sched_barrier(0);
            if (t + 2 < NT) { __asm__ __volatile__("s_waitcnt vmcnt(3)" ::: "memory"); }
            else            { __asm__ __volatile__("s_waitcnt vmcnt(0)" ::: "memory"); }
            __builtin_amdgcn_s_barrier();
            __builtin_amdgcn_sched_barrier(0);
        }
        cur = (cur == 2) ? 0 : cur + 1;
    }

    const int col = lane & 15;
    const int rb  = (lane >> 4) * 4;
    #pragma unroll
    for (int i = 0; i < 4; ++i) {
        #pragma unroll
        for (int j = 0; j < 4; ++j) {
            const int n = n0 + wn + j * 16 + col;
            #pragma unroll
            for (int r = 0; r < 4; ++r) {
                const int m = m0 + wm + i * 16 + rb + r;
                float v = acc[i][j][r];
                if (bias)    v += bias[n];
                if (do_relu) v = fmaxf(v, 0.f);
                if (resid)   v += b2f(resid[(size_t)m * ldc + n]);
                if (CoF) CoF[(size_t)m * ldc + n] = v;
                else     CoB[(size_t)m * ldc + n] = f2b(v);
            }
        }
    }
}

// ---- MFMA flash attention v3 + T5 setprio + T13 defer-max (round-9 best) ----
// NOTE (r10): no branches inside the unrolled QK/exp loops — breaks the
// static schedule (+4.3M bank conflicts, VGPR 132, attn 125->172 us).
__global__ __launch_bounds__(256) void attn_mfma3(
    const u16* __restrict__ QKV, u16* __restrict__ Y)
{
    __shared__ __align__(16) u16 Kl[2][64 * 64];     // 16 KB
    __shared__ __align__(16) u16 Vt[2][64 * 64];     // 16 KB (transposed [d][s])
    __shared__ __align__(16) u16 Pl[4][16 * 64];     // 8 KB per-wave P^T [q][s]

    const int tid  = threadIdx.x;
    const int wave = tid >> 6, lane = tid & 63;
    const int ln = lane & 15, quad = lane >> 4;
    const int idx = blockIdx.x;
    const int bh = idx & 63;                         // same bh -> same idx%8 (XCD)
    const int qt = 15 - (idx >> 6);                  // heavy q-tiles dispatch first
    const int b = bh >> 4, h = bh & 15;
    const int q0 = qt << 7;
    const int bT = b * kT;
    const int qgw = q0 + wave * 32;
    const float scale = 0.03125f;                    // 1024^-0.5 (full embed dim)

    const u16* kvbase = QKV + (size_t)bT * k3C + kC + h * 64;  // K base (V = +kC)

    const int sK = tid >> 3, cK = tid & 7;
    const int sV = (tid >> 3) * 2, cV = tid & 7;
    const int kwa0 = (sK << 6) + ((cK ^ (sK & 7)) << 3);
    const int kwa1 = kwa0 + (32 << 6);

    bf16x8 qa[2][2];
    #pragma unroll
    for (int qsub = 0; qsub < 2; ++qsub) {
        const size_t qb = ((size_t)bT + qgw + 16 * qsub + ln) * k3C + h * 64;
        qa[qsub][0] = *(const bf16x8*)(QKV + qb + quad * 8);
        qa[qsub][1] = *(const bf16x8*)(QKV + qb + 32 + quad * 8);
    }

    f32x4 acco[2][4];
    #pragma unroll
    for (int qsub = 0; qsub < 2; ++qsub)
        #pragma unroll
        for (int jd = 0; jd < 4; ++jd) acco[qsub][jd] = (f32x4){0.f, 0.f, 0.f, 0.f};
    float mrun[2] = {-1e30f, -1e30f}, lrun[2] = {0.f, 0.f};
    u16* Pw = Pl[wave];

    const int ntiles = 2 * qt + 2;                   // always even

    auto loadkv = [&](int s0p, uint4& k0, uint4& k1, uint4& v0, uint4& v1) {
        const u16* kg = kvbase + (size_t)(s0p + sK) * k3C + cK * 8;
        k0 = *(const uint4*)kg;
        k1 = *(const uint4*)(kg + (size_t)32 * k3C);
        const u16* vg = kvbase + kC + (size_t)(s0p + sV) * k3C + cV * 8;
        v0 = *(const uint4*)vg;
        v1 = *(const uint4*)(vg + k3C);
    };
    auto stage = [&](u16* Kb, u16* Vb, const uint4& k0, const uint4& k1,
                     const uint4& v0, const uint4& v1) {
        *(uint4*)&Kb[kwa0] = k0;
        *(uint4*)&Kb[kwa1] = k1;
        const u16* t0 = (const u16*)&v0;
        const u16* t1 = (const u16*)&v1;
        #pragma unroll
        for (int i = 0; i < 8; ++i) {
            const int d = cV * 8 + i;
            const int chunk = ((sV >> 3) ^ (d & 7) ^ ((d >> 3) & 7)) & 7;
            ushort2 pr; pr.x = t0[i]; pr.y = t1[i];
            *(ushort2*)&Vb[(d << 6) + (chunk << 3) + (sV & 7)] = pr;
        }
    };
    auto compute = [&](int t, const u16* Kb, const u16* Vb) {
        const int s0 = t << 6;
        if (s0 > qgw + 31) return;                   // wave fully masked this tile
        f32x4 accs[2][4];
        #pragma unroll
        for (int qsub = 0; qsub < 2; ++qsub)
            #pragma unroll
            for (int j = 0; j < 4; ++j) accs[qsub][j] = (f32x4){0.f, 0.f, 0.f, 0.f};
        __builtin_amdgcn_s_setprio(1);               // T5: QK cluster
        #pragma unroll
        for (int ks = 0; ks < 2; ++ks) {
            #pragma unroll
            for (int j = 0; j < 4; ++j) {
                const int s = j * 16 + ln;
                bf16x8 kb = *(const bf16x8*)&Kb[(s << 6) + ((((quad + 4 * ks) ^ (s & 7)) & 7) << 3)];
                accs[0][j] = __builtin_amdgcn_mfma_f32_16x16x32_bf16(kb, qa[0][ks], accs[0][j], 0, 0, 0);
                accs[1][j] = __builtin_amdgcn_mfma_f32_16x16x32_bf16(kb, qa[1][ks], accs[1][j], 0, 0, 0);
            }
        }
        __builtin_amdgcn_s_setprio(0);
        bf16x8 vfr[4][2];
        #pragma unroll
        for (int jd = 0; jd < 4; ++jd) {
            const int d = jd * 16 + ln;
            #pragma unroll
            for (int ks = 0; ks < 2; ++ks)
                vfr[jd][ks] = *(const bf16x8*)&Vb[(d << 6) + ((((quad + 4 * ks) ^ (d & 7) ^ ((d >> 3) & 7)) & 7) << 3)];
        }
        #pragma unroll
        for (int qsub = 0; qsub < 2; ++qsub) {
            const int qg = qgw + 16 * qsub + ln;
            float part = -1e30f;
            #pragma unroll
            for (int j = 0; j < 4; ++j) {
                #pragma unroll
                for (int r = 0; r < 4; ++r) {
                    const int sg = s0 + j * 16 + quad * 4 + r;
                    float v = accs[qsub][j][r] * scale;
                    v = (sg <= qg) ? v : -1e30f;
                    accs[qsub][j][r] = v;
                    part = fmaxf(part, v);
                }
            }
            float mx = fmaxf(part, __shfl_xor(part, 16));
            mx = fmaxf(mx, __shfl_xor(mx, 32));
            const bool skip = __all(mx - mrun[qsub] <= 8.0f);
            const float mn = skip ? mrun[qsub] : fmaxf(mrun[qsub], mx);
            float ls = 0.f;
            #pragma unroll
            for (int j = 0; j < 4; ++j)
                #pragma unroll
                for (int r = 0; r < 4; ++r) {
                    const float p = __expf(accs[qsub][j][r] - mn);
                    accs[qsub][j][r] = p;
                    ls += p;
                }
            ls += __shfl_xor(ls, 16);
            ls += __shfl_xor(ls, 32);
            if (skip) {
                lrun[qsub] += ls;
            } else {
                const float al = __expf(mrun[qsub] - mn);
                mrun[qsub] = mn;
                lrun[qsub] = lrun[qsub] * al + ls;
                #pragma unroll
                for (int jd = 0; jd < 4; ++jd)
                    #pragma unroll
                    for (int r = 0; r < 4; ++r)
                        acco[qsub][jd][r] *= al;
            }
            #pragma unroll
            for (int j = 0; j < 4; ++j) {
                ushort4 pk;
                pk.x = f2b(accs[qsub][j][0]); pk.y = f2b(accs[qsub][j][1]);
                pk.z = f2b(accs[qsub][j][2]); pk.w = f2b(accs[qsub][j][3]);
                const int chunk = ((2 * j + (quad >> 1)) ^ (ln & 7)) & 7;
                *(ushort4*)&Pw[(ln << 6) + (chunk << 3) + ((quad & 1) << 2)] = pk;
            }
            __builtin_amdgcn_s_setprio(1);           // T5: PV cluster
            #pragma unroll
            for (int ks = 0; ks < 2; ++ks) {
                bf16x8 pb = *(const bf16x8*)&Pw[(ln << 6) + ((((4 * ks + quad) ^ (ln & 7)) & 7) << 3)];
                #pragma unroll
                for (int jd = 0; jd < 4; ++jd)
                    acco[qsub][jd] = __builtin_amdgcn_mfma_f32_16x16x32_bf16(
                        vfr[jd][ks], pb, acco[qsub][jd], 0, 0, 0);
            }
            __builtin_amdgcn_s_setprio(0);
        }
    };

    uint4 ka0, ka1, va0, va1, kb0, kb1, vb0, vb1;
    loadkv(0, ka0, ka1, va0, va1);
    for (int t = 0; t < ntiles; t += 2) {
        stage(Kl[0], Vt[0], ka0, ka1, va0, va1);
        loadkv((t + 1) << 6, kb0, kb1, vb0, vb1);    // t+1 < ntiles (ntiles even)
        lds_barrier();
        compute(t, Kl[0], Vt[0]);
        stage(Kl[1], Vt[1], kb0, kb1, vb0, vb1);
        loadkv(((t + 2) < ntiles ? (t + 2) : 0) << 6, ka0, ka1, va0, va1);
        lds_barrier();
        compute(t + 1, Kl[1], Vt[1]);
    }

    // epilogue: O^T row d = jd*16 + quad*4 + r, col q = ln
    #pragma unroll
    for (int qsub = 0; qsub < 2; ++qsub) {
        const float inv = 1.f / lrun[qsub];
        const size_t yrow = ((size_t)bT + qgw + 16 * qsub + ln) * kC + h * 64;
        #pragma unroll
        for (int jd = 0; jd < 4; ++jd) {
            ushort4 ov;
            ov.x = f2b(acco[qsub][jd][0] * inv);
            ov.y = f2b(acco[qsub][jd][1] * inv);
            ov.z = f2b(acco[qsub][jd][2] * inv);
            ov.w = f2b(acco[qsub][jd][3] * inv);
            *(ushort4*)(Y + yrow + jd * 16 + quad * 4) = ov;
        }
    }
}

extern "C" void kernel_launch(void* const* d_in, const int* in_sizes, int n_in,
                              void* d_out, int out_size, void* d_ws, size_t ws_size,
                              hipStream_t stream) {
    const float* x     = (const float*)d_in[0];
    const float* Wq    = (const float*)d_in[1];
    const float* Wk    = (const float*)d_in[2];
    const float* Wv    = (const float*)d_in[3];
    const float* Wproj = (const float*)d_in[4];
    const float* bproj = (const float*)d_in[5];
    const float* W1    = (const float*)d_in[6];
    const float* b1    = (const float*)d_in[7];
    const float* W2    = (const float*)d_in[8];
    const float* b2    = (const float*)d_in[9];

    // Workspace (bf16 elements). QKV (live 2-3) aliases ffh (live 5-6).
    u16* ws      = (u16*)d_ws;
    u16* QKV     = ws;                                  // [8192,3072]
    u16* ffh     = ws;                                  // [8192,4096]
    u16* attn_y  = ws + (size_t)kM * kFF;               // [8192,1024]
    u16* xb      = attn_y  + (size_t)kM * kC;           // [8192,1024]
    u16* res1    = xb      + (size_t)kM * kC;           // [8192,1024]
    u16* Wqkv_t  = res1    + (size_t)kM * kC;           // [3072,1024]
    u16* Wproj_t = Wqkv_t  + (size_t)k3C * kC;          // [1024,1024]
    u16* W1t     = Wproj_t + (size_t)kC * kC;           // [4096,1024]
    u16* W2t     = W1t     + (size_t)kFF * kC;          // [1024,4096]
    float* out   = (float*)d_out;

    // 0. converts / repacks
    cvt_f32_bf16<<<(kM * kC / 4 + 255) / 256, 256, 0, stream>>>(x, xb, kM * kC / 4);
    repack_qkv_t<<<dim3(2, kC / 32, 48), dim3(32, 8), 0, stream>>>(Wq, Wk, Wv, Wqkv_t);
    transpose_cvt<<<dim3(kC / 32, kC / 32),  dim3(32, 8), 0, stream>>>(Wproj, kC, kC, Wproj_t);
    transpose_cvt<<<dim3(kFF / 32, kC / 32), dim3(32, 8), 0, stream>>>(W1, kC, kFF, W1t);
    transpose_cvt<<<dim3(kC / 32, kFF / 32), dim3(32, 8), 0, stream>>>(W2, kFF, kC, W2t);

    // 1. QKV = xb @ Wqkv_t^T        (32*24 = 768 blocks)
    gemm_bt_k32r<<<dim3((kM / 256) * (k3C / 128)), 512, 0, stream>>>(
        xb, kC, Wqkv_t, kC, kC, nullptr, nullptr, nullptr, QKV, k3C, 0, k3C / 128);
    // 2. attention -> attn_y bf16
    attn_mfma3<<<dim3(1024), 256, 0, stream>>>(QKV, attn_y);
    // 3. res1 = attn_y @ Wproj + bproj + xb   (32*8 = 256 blocks)
    gemm_bt_k32r<<<dim3((kM / 256) * (kC / 128)), 512, 0, stream>>>(
        attn_y, kC, Wproj_t, kC, kC, bproj, xb, nullptr, res1, kC, 0, kC / 128);
    // 4. ffh = relu(res1 @ W1 + b1)           (32*32 = 1024 blocks)
    gemm_bt_k32r<<<dim3((kM / 256) * (kFF / 128)), 512, 0, stream>>>(
        res1, kC, W1t, kC, kC, b1, nullptr, nullptr, ffh, kFF, 1, kFF / 128);
    // 5. out = ffh @ W2 + b2 + res1 -> f32    (32*8 = 256 blocks)
    gemm_bt_k32r<<<dim3((kM / 256) * (kC / 128)), 512, 0, stream>>>(
        ffh, kFF, W2t, kFF, kFF, b2, res1, out, nullptr, kC, 0, kC / 128);
}